// Round 9
// baseline (616.641 us; speedup 1.0000x reference)
//
#include <hip/hip_runtime.h>
#include <stdint.h>

// AudioSNN: conv1(1->32)+spike+pool -> conv2(32->64)+spike+pool -> fc1
// -> 25-step LIF (fc2, fc3).
// ALL matmul-shaped compute on MFMA via exact fp16 2-way splits (err ~2^-23,
// absmax 0 in R3..R8). R9: k_conv occupancy 2->3 blocks/CU — cin stored as u8
// (24.5 KB, pad 40 => 8B-aligned single ds_read_b64 B-frags + exact u8->f16
// cvt) and phase-2 split into two acc[4][4] passes (64 acc regs live, unroll 1)
// under __launch_bounds__(256,3). R7 lesson: unified VGPR+AGPR file — watch
// FETCH_SIZE for spill storms.
//
// ws layout:
//   part f32 [32][1024][256]       @0     32 MB
//   xq   u8  [1024][8192]          @32M    8 MB
//   afrag f16 [72][512]+[2][512]   @41M   76 KB (conv2 frags + conv1 frags)
//   w1s  f16 [2][16][256][512]     @42M    8 MB (fc1 A fragments hi/lo planes)

#define NSTEP 25

using half8   = __attribute__((ext_vector_type(8))) _Float16;
using half4v  = __attribute__((ext_vector_type(4))) _Float16;
using float4v = __attribute__((ext_vector_type(4))) float;
using float16v = __attribute__((ext_vector_type(16))) float;

__device__ __forceinline__ float lif_update(float mem, float cur) {
#pragma clang fp contract(off)
  float reset = (mem > 1.0f) ? 1.0f : 0.0f;
  float m = 0.95f * mem;
  m = m + cur;
  m = m - reset;
  return m;
}

// ------------------------------------------------- weight prep (all fragments)
// blocks 0..71: conv2 afrag; block 72: conv1 frags; 73..1096: fc1 w1s.
__global__ __launch_bounds__(256) void k_prep(const float* __restrict__ w2c,
                                              const float* __restrict__ w1c,
                                              const float* __restrict__ w1,
                                              _Float16* __restrict__ afrag,
                                              _Float16* __restrict__ w1s) {
  const int b = blockIdx.x;
  const int t = threadIdx.x;
  if (b < 72) {
    if (t < 64) {
      const int tp = b >> 3;
      const int mt = (b & 7) >> 1;
      const int sp = b & 1;
      const int m = t & 15, quad = t >> 4;
#pragma unroll
      for (int j = 0; j < 8; ++j) {
        int ch = quad * 8 + j;
        int oc = mt * 16 + m;
        float wv = w2c[(size_t)(oc * 32 + ch) * 9 + tp];
        float hi = (float)(_Float16)wv;
        _Float16 val = (sp == 0) ? (_Float16)wv : (_Float16)(wv - hi);
        afrag[(size_t)b * 512 + t * 8 + j] = val;
      }
    }
    return;
  }
  if (b == 72) {
    // conv1 A-frags: A[m=oc=lane&31][k=(lane>>5)*8+j]; k<9 = tap k, else 0.
    if (t < 64) {
      const int m = t & 31, kb = t >> 5;
      _Float16* c1f = afrag + 72 * 512;
#pragma unroll
      for (int j = 0; j < 8; ++j) {
        int k = kb * 8 + j;
        float wv = (k < 9) ? w1c[m * 9 + k] : 0.0f;
        float hi = (float)(_Float16)wv;
        c1f[t * 8 + j] = (_Float16)wv;
        c1f[512 + t * 8 + j] = (_Float16)(wv - hi);
      }
    }
    return;
  }
  const int W = (b - 73) * 4 + (t >> 6);  // 0..4095 = mt*256+kcg
  const int lane = t & 63;
  const int mt = W >> 8, kcg = W & 255;
  const int m = lane & 15, quad = lane >> 4;
  const float* src = w1 + (size_t)(mt * 16 + m) * 8192 + kcg * 32 + quad * 8;
  float4 u0 = *(const float4*)src;
  float4 u1 = *(const float4*)(src + 4);
  float wv[8] = {u0.x, u0.y, u0.z, u0.w, u1.x, u1.y, u1.z, u1.w};
  half8 hi, lo;
#pragma unroll
  for (int e = 0; e < 8; ++e) {
    float h = (float)(_Float16)wv[e];
    hi[e] = (_Float16)wv[e];
    lo[e] = (_Float16)(wv[e] - h);
  }
  _Float16* dst = w1s + ((size_t)W) * 512 + lane * 8;
  *(half8*)dst = hi;
  *(half8*)(dst + (size_t)16 * 256 * 512) = lo;   // lo plane at +4 MB
}

// -------------------------------------------- fused conv1+conv2 (one sample)
// Phase 1 (MFMA 32x32x16): conv1 as tap-packed GEMM, spike+pool -> cin (u8).
// Phase 2 (MFMA 16x16x32): conv2 implicit GEMM from cin, spike+pool -> xq.
__global__ __launch_bounds__(256, 3) void k_conv(const float* __restrict__ x,
                                                 const float* __restrict__ b1c,
                                                 const _Float16* __restrict__ afrag,
                                                 const float* __restrict__ b2c,
                                                 uint8_t* __restrict__ xq) {
  __shared__ uint8_t cin[34 * 18 * 40];   // [row 34][col 18][ch pad 40] 24480 B
  __shared__ _Float16 xs2[2 * 2244];      // conv1 input hi/lo planes (66x34)
  __shared__ float blds[32];
  const int t = threadIdx.x;
  const int s = blockIdx.x;
  const int lane = t & 63;
  const int wave = __builtin_amdgcn_readfirstlane(t >> 6);

  {  // zero cin + xs2 (covers halos)
    uint4 z4 = {0u, 0u, 0u, 0u};
    uint4* cp = (uint4*)cin;
    for (int idx = t; idx < 1530; idx += 256) cp[idx] = z4;
    half8 z = {};
    half8* xp = (half8*)xs2;
    for (int idx = t; idx < 561; idx += 256) xp[idx] = z;
  }
  if (t < 32) blds[t] = b1c[t];
  __syncthreads();

  {  // stage x interior as hi/lo fp16 planes
    const float* xs = x + (size_t)s * (64 * 32);
#pragma unroll
    for (int r = 0; r < 2; ++r) {
      int g = t + r * 256;                // 512 groups = 64 rows x 8 quads
      int y = g >> 3, q = g & 7;
      float4 v = *(const float4*)(xs + y * 32 + q * 4);
      float f[4] = {v.x, v.y, v.z, v.w};
#pragma unroll
      for (int e = 0; e < 4; ++e) {
        int ad = (y + 1) * 34 + q * 4 + 1 + e;
        _Float16 h = (_Float16)f[e];
        xs2[ad] = h;
        xs2[2244 + ad] = (_Float16)(f[e] - (float)h);
      }
    }
  }
  __syncthreads();

  // ---- phase 1: conv1 on MFMA. One 32x32x16 tile = 32 oc x one image row.
  {
    const _Float16* c1f = afrag + 72 * 512;
    half8 a1h = *(const half8*)(c1f + lane * 8);
    half8 a1l = *(const half8*)(c1f + 512 + lane * 8);
    const int xcol = lane & 31;
    const int hf = lane >> 5;
    float16v accb;
#pragma unroll
    for (int r = 0; r < 16; ++r)
      accb[r] = blds[(r & 3) + 8 * (r >> 2) + 4 * hf];   // bias as C-init
    const int wrow = wave * 16;
#pragma unroll
    for (int pp = 0; pp < 8; ++pp) {
      float16v acc0 = accb, acc1 = accb;
#pragma unroll
      for (int rr = 0; rr < 2; ++rr) {
        const int y = wrow + pp * 2 + rr;
        half8 bh = {}, blo = {};
        if (lane < 32) {
#pragma unroll
          for (int j = 0; j < 8; ++j) {       // taps 0..7
            int ad = (y + j / 3) * 34 + xcol + (j % 3);
            bh[j] = xs2[ad];
            blo[j] = xs2[2244 + ad];
          }
        } else {                              // tap 8 + zeros
          int ad = (y + 2) * 34 + xcol + 2;
          bh[0] = xs2[ad];
          blo[0] = xs2[2244 + ad];
        }
        // (wh+wl)(xh+xl) minus wl*xl (~2^-24): 3 MFMAs
        if (rr == 0) {
          acc0 = __builtin_amdgcn_mfma_f32_32x32x16_f16(a1h, bh, acc0, 0, 0, 0);
          acc0 = __builtin_amdgcn_mfma_f32_32x32x16_f16(a1l, bh, acc0, 0, 0, 0);
          acc0 = __builtin_amdgcn_mfma_f32_32x32x16_f16(a1h, blo, acc0, 0, 0, 0);
        } else {
          acc1 = __builtin_amdgcn_mfma_f32_32x32x16_f16(a1h, bh, acc1, 0, 0, 0);
          acc1 = __builtin_amdgcn_mfma_f32_32x32x16_f16(a1l, bh, acc1, 0, 0, 0);
          acc1 = __builtin_amdgcn_mfma_f32_32x32x16_f16(a1h, blo, acc1, 0, 0, 0);
        }
      }
      // spike + 2x2 pool (y-pair in-lane, x via shfl) -> cin u8 counts
      int cr[16];
#pragma unroll
      for (int r = 0; r < 16; ++r) {
        int c = ((acc0[r] > 1.0f) ? 1 : 0) + ((acc1[r] > 1.0f) ? 1 : 0);
        cr[r] = c + __shfl_xor(c, 1, 64);
      }
      if ((xcol & 1) == 0) {
        const int py = 8 * wave + pp;
        const int px = xcol >> 1;
        const int base = ((py + 1) * 18 + (px + 1)) * 40;
#pragma unroll
        for (int r = 0; r < 16; ++r)
          cin[base + (r & 3) + 8 * (r >> 2) + 4 * hf] = (uint8_t)cr[r];
      }
    }
  }
  __syncthreads();

  // ---- phase 2: conv2 MFMA (M=64 oc, N=512 pos, K=32 ch per tap x 9),
  // split into two nt-halves so only acc[4][4] (64 regs) is live at once.
  const int xlane = lane & 15, quad = lane >> 4;

  float bw[4][4];
#pragma unroll
  for (int mt = 0; mt < 4; ++mt)
#pragma unroll
    for (int r = 0; r < 4; ++r) bw[mt][r] = b2c[mt * 16 + quad * 4 + r];

  uint8_t* xqs = xq + (size_t)s * 8192;
  const int px = xlane >> 1;
  const bool writer = (xlane & 1) == 0;

#pragma unroll 1
  for (int ntp = 0; ntp < 2; ++ntp) {
    float4v acc[4][4];
#pragma unroll
    for (int mt = 0; mt < 4; ++mt)
#pragma unroll
      for (int n4 = 0; n4 < 4; ++n4) acc[mt][n4] = (float4v){0.f, 0.f, 0.f, 0.f};

    for (int ky = 0; ky < 3; ++ky)
      for (int kx = 0; kx < 3; ++kx) {
        const int tp = ky * 3 + kx;
        half8 a[4][2];
#pragma unroll
        for (int mt = 0; mt < 4; ++mt)
#pragma unroll
          for (int sp = 0; sp < 2; ++sp)
            a[mt][sp] = *(const half8*)(afrag +
                          ((size_t)((tp * 4 + mt) * 2 + sp)) * 512 + lane * 8);
#pragma unroll
        for (int n4 = 0; n4 < 4; ++n4) {
          int row = wave * 8 + ntp * 4 + n4 + ky;
          int col = xlane + kx;
          const uint32_t* bp = (const uint32_t*)&cin[(row * 18 + col) * 40 + quad * 8];
          uint32_t w0 = bp[0], w1 = bp[1];      // 8B-aligned ds_read_b64
          half8 b;
#pragma unroll
          for (int e = 0; e < 4; ++e)
            b[e] = (_Float16)(float)((w0 >> (e * 8)) & 0xffu);
#pragma unroll
          for (int e = 0; e < 4; ++e)
            b[4 + e] = (_Float16)(float)((w1 >> (e * 8)) & 0xffu);
#pragma unroll
          for (int mt = 0; mt < 4; ++mt) {
            acc[mt][n4] = __builtin_amdgcn_mfma_f32_16x16x32_f16(a[mt][0], b,
                                                                 acc[mt][n4], 0, 0, 0);
            acc[mt][n4] = __builtin_amdgcn_mfma_f32_16x16x32_f16(a[mt][1], b,
                                                                 acc[mt][n4], 0, 0, 0);
          }
        }
      }

    // epilogue for this nt-half: pooled rows py = wave*4 + ntp*2 + {0,1}
#pragma unroll
    for (int mt = 0; mt < 4; ++mt)
#pragma unroll
      for (int pr2 = 0; pr2 < 2; ++pr2) {
        int py = wave * 4 + ntp * 2 + pr2;
#pragma unroll
        for (int r = 0; r < 4; ++r) {
          float v0 = 0.25f * acc[mt][2 * pr2 + 0][r] + bw[mt][r];
          float v1 = 0.25f * acc[mt][2 * pr2 + 1][r] + bw[mt][r];
          int c = ((v0 > 1.0f) ? 1 : 0) + ((v1 > 1.0f) ? 1 : 0);
          c += __shfl_xor(c, 1, 64);
          if (writer) {
            int oc = mt * 16 + quad * 4 + r;
            xqs[oc * 128 + py * 8 + px] = (uint8_t)c;
          }
        }
      }
  }
}

// ---------------------------------------------------------------- fc1 (MFMA)
__global__ __launch_bounds__(256, 2) void k_fc1(const uint8_t* __restrict__ xq,
                                                const _Float16* __restrict__ w1s,
                                                float* __restrict__ part) {
  __shared__ _Float16 bt[8 * 4 * 64 * 8];   // [kc][nt][lane][8] = 32 KB
  const int t = threadIdx.x;
  const int sblk = blockIdx.x >> 5;   // 16 sample tiles of 64
  const int kblk = blockIdx.x & 31;   // 32 K slices of 256
  const int sb = sblk * 64;

  {  // stage B: u8 counts -> fp16, frag-ready
    const int row = t >> 2;
    const int seg = t & 3;
    const int nt = row >> 4, n16 = row & 15;
    const uint8_t* src = xq + (size_t)(sb + row) * 8192 + kblk * 256 + seg * 64;
#pragma unroll
    for (int q = 0; q < 4; ++q) {
      uint4 u = *(const uint4*)(src + q * 16);
      uint32_t wd[4] = {u.x, u.y, u.z, u.w};
#pragma unroll
      for (int g = 0; g < 2; ++g) {
        half8 h;
#pragma unroll
        for (int e = 0; e < 8; ++e) {
          uint32_t word = wd[g * 2 + (e >> 2)];
          h[e] = (_Float16)(unsigned short)((word >> ((e & 3) * 8)) & 0xffu);
        }
        int koff = seg * 64 + q * 16 + g * 8;
        int kc = koff >> 5, quad = (koff >> 3) & 3;
        *(half8*)&bt[(((kc * 4 + nt) * 64) + quad * 16 + n16) * 8] = h;
      }
    }
  }
  __syncthreads();

  const int lane = t & 63;
  const int wave = __builtin_amdgcn_readfirstlane(t >> 6);

  float4v acc[4][4];
#pragma unroll
  for (int mt = 0; mt < 4; ++mt)
#pragma unroll
    for (int nt = 0; nt < 4; ++nt) acc[mt][nt] = (float4v){0.f, 0.f, 0.f, 0.f};

#pragma unroll
  for (int kc = 0; kc < 8; ++kc) {
    const int kcg = kblk * 8 + kc;
    half8 b[4];
#pragma unroll
    for (int nt = 0; nt < 4; ++nt)
      b[nt] = *(const half8*)&bt[((kc * 4 + nt) * 64 + lane) * 8];
#pragma unroll
    for (int mt = 0; mt < 4; ++mt) {
      const _Float16* ap = w1s + ((size_t)((wave * 4 + mt) * 256 + kcg)) * 512 + lane * 8;
      half8 ah = *(const half8*)ap;
      half8 al = *(const half8*)(ap + (size_t)16 * 256 * 512);
#pragma unroll
      for (int nt = 0; nt < 4; ++nt) {
        acc[mt][nt] = __builtin_amdgcn_mfma_f32_16x16x32_f16(ah, b[nt],
                                                             acc[mt][nt], 0, 0, 0);
        acc[mt][nt] = __builtin_amdgcn_mfma_f32_16x16x32_f16(al, b[nt],
                                                             acc[mt][nt], 0, 0, 0);
      }
    }
  }

  const int n16 = lane & 15, quad = lane >> 4;
  float* pp = part + (size_t)kblk * (1024 * 256);
#pragma unroll
  for (int mt = 0; mt < 4; ++mt)
#pragma unroll
    for (int nt = 0; nt < 4; ++nt) {
      int s = sb + nt * 16 + n16;
      int ob = wave * 64 + mt * 16 + quad * 4;
      float4 v = {0.25f * acc[mt][nt][0], 0.25f * acc[mt][nt][1],
                  0.25f * acc[mt][nt][2], 0.25f * acc[mt][nt][3]};
      *(float4*)&pp[(size_t)s * 256 + ob] = v;
    }
}

// ---------------------------------------------------------------- LIF recurrence
__global__ __launch_bounds__(512, 2) void k_lif(const float* __restrict__ part,
                                                const float* __restrict__ b1,
                                                const float* __restrict__ w2,   // [128][256]
                                                const float* __restrict__ b2,
                                                const float* __restrict__ w3,   // [10][128]
                                                const float* __restrict__ b3,
                                                float* __restrict__ out) {
  __shared__ float cur3l[1024];     // [s4][o256]
  __shared__ _Float16 spk3[1152];   // [oct32][s4][8] + pad
  __shared__ _Float16 spk4[640];    // [oct16][s4][8] + pad
  const int t = threadIdx.x;
  const int sb = blockIdx.x * 4;    // 4 samples/block, grid 256 = 1 block/CU
  const int lane = t & 63;
  const int wave = __builtin_amdgcn_readfirstlane(t >> 6);
  const int n16 = lane & 15;
  const int quad = lane >> 4;

  // ---- fc1 reduce: deterministic kb-order sum + bias-last
#pragma unroll
  for (int r = 0; r < 2; ++r) {
    int v = t + r * 512;            // = s*256 + o
    int s = v >> 8, o = v & 255;
    float sum = 0.0f;
    for (int kb = 0; kb < 32; ++kb)
      sum += part[(size_t)kb * (1024 * 256) + (size_t)(sb + s) * 256 + o];
    cur3l[v] = sum + b1[o];
  }

  half8 a2h[8], a2l[8];
  {
    const float* wr = w2 + (size_t)(wave * 16 + n16) * 256 + quad * 8;
#pragma unroll
    for (int kt = 0; kt < 8; ++kt) {
      float4 u0 = *(const float4*)(wr + kt * 32);
      float4 u1 = *(const float4*)(wr + kt * 32 + 4);
      float wv[8] = {u0.x, u0.y, u0.z, u0.w, u1.x, u1.y, u1.z, u1.w};
#pragma unroll
      for (int e = 0; e < 8; ++e) {
        float hi = (float)(_Float16)wv[e];
        a2h[kt][e] = (_Float16)wv[e];
        a2l[kt][e] = (_Float16)(wv[e] - hi);
      }
    }
  }
  const float4 b2v = *(const float4*)(b2 + wave * 16 + quad * 4);
  float mem4[4] = {0.f, 0.f, 0.f, 0.f};

  half8 a3h[4], a3l[4];
#pragma unroll
  for (int kt = 0; kt < 4; ++kt) { a3h[kt] = (half8){}; a3l[kt] = (half8){}; }
  if (n16 < 10) {
    const float* wr = w3 + (size_t)n16 * 128 + quad * 8;
#pragma unroll
    for (int kt = 0; kt < 4; ++kt) {
      float4 u0 = *(const float4*)(wr + kt * 32);
      float4 u1 = *(const float4*)(wr + kt * 32 + 4);
      float wv[8] = {u0.x, u0.y, u0.z, u0.w, u1.x, u1.y, u1.z, u1.w};
#pragma unroll
      for (int e = 0; e < 8; ++e) {
        float hi = (float)(_Float16)wv[e];
        a3h[kt][e] = (_Float16)wv[e];
        a3l[kt][e] = (_Float16)(wv[e] - hi);
      }
    }
  }
  float b3r[4];
#pragma unroll
  for (int r = 0; r < 4; ++r) {
    int cls = quad * 4 + r;
    b3r[r] = (cls < 10) ? b3[cls] : 0.0f;
  }
  float mem5[4] = {0.f, 0.f, 0.f, 0.f};

  __syncthreads();

  float mem3[8], cur3r[8];
  if (t < 128) {
    const int o = t >> 2, s = t & 3;
    const float* cp = &cur3l[s * 256 + o * 8];
    float4 c0 = *(const float4*)cp;
    float4 c1 = *(const float4*)(cp + 4);
    cur3r[0] = c0.x; cur3r[1] = c0.y; cur3r[2] = c0.z; cur3r[3] = c0.w;
    cur3r[4] = c1.x; cur3r[5] = c1.y; cur3r[6] = c1.z; cur3r[7] = c1.w;
#pragma unroll
    for (int j = 0; j < 8; ++j) mem3[j] = 0.0f;
  }

  for (int step = 0; step < NSTEP; ++step) {
    if (t < 128) {
      const int o = t >> 2, s = t & 3;
      half8 sv;
#pragma unroll
      for (int j = 0; j < 8; ++j) {
        mem3[j] = lif_update(mem3[j], cur3r[j]);
        sv[j] = (_Float16)((mem3[j] > 1.0f) ? 1.0f : 0.0f);
      }
      *(half8*)&spk3[o * 32 + s * 8] = sv;
    }
    __syncthreads();
    {
      float4v acc0 = {0.f, 0.f, 0.f, 0.f}, acc1 = {0.f, 0.f, 0.f, 0.f};
#pragma unroll
      for (int kt = 0; kt < 8; ++kt) {
        half8 b = *(const half8*)&spk3[(kt * 4 + quad) * 32 + n16 * 8];
        acc0 = __builtin_amdgcn_mfma_f32_16x16x32_f16(a2h[kt], b, acc0, 0, 0, 0);
        acc1 = __builtin_amdgcn_mfma_f32_16x16x32_f16(a2l[kt], b, acc1, 0, 0, 0);
      }
      if (n16 < 4) {
        half4v pk;
#pragma unroll
        for (int r = 0; r < 4; ++r) {
          float cur4 = (acc0[r] + acc1[r]) + b2v[r];
          mem4[r] = lif_update(mem4[r], cur4);
          pk[r] = (_Float16)((mem4[r] > 1.0f) ? 1.0f : 0.0f);
        }
        *(half4v*)&spk4[(wave * 2 + (quad >> 1)) * 32 + n16 * 8 + (quad & 1) * 4] = pk;
      }
    }
    __syncthreads();
    if (wave == 0) {
      float4v c0 = {0.f, 0.f, 0.f, 0.f}, c1 = {0.f, 0.f, 0.f, 0.f};
#pragma unroll
      for (int kt = 0; kt < 4; ++kt) {
        half8 b = *(const half8*)&spk4[(kt * 4 + quad) * 32 + n16 * 8];
        c0 = __builtin_amdgcn_mfma_f32_16x16x32_f16(a3h[kt], b, c0, 0, 0, 0);
        c1 = __builtin_amdgcn_mfma_f32_16x16x32_f16(a3l[kt], b, c1, 0, 0, 0);
      }
#pragma unroll
      for (int r = 0; r < 4; ++r) {
        int cls = quad * 4 + r;
        float cur5 = (c0[r] + c1[r]) + b3r[r];
        mem5[r] = lif_update(mem5[r], cur5);
        if (n16 < 4 && cls < 10)
          out[(size_t)step * 10240 + (size_t)(sb + n16) * 10 + cls] =
              (mem5[r] > 1.0f) ? 1.0f : 0.0f;
      }
    }
    __syncthreads();
  }
}

// ---------------------------------------------------------------- launcher
extern "C" void kernel_launch(void* const* d_in, const int* in_sizes, int n_in,
                              void* d_out, int out_size, void* d_ws, size_t ws_size,
                              hipStream_t stream) {
  (void)in_sizes; (void)n_in; (void)out_size; (void)ws_size;
  const float* x   = (const float*)d_in[0];
  const float* w1c = (const float*)d_in[1];
  const float* b1c = (const float*)d_in[2];
  const float* w2c = (const float*)d_in[3];
  const float* b2c = (const float*)d_in[4];
  const float* fw1 = (const float*)d_in[5];
  const float* fb1 = (const float*)d_in[6];
  const float* fw2 = (const float*)d_in[7];
  const float* fb2 = (const float*)d_in[8];
  const float* fw3 = (const float*)d_in[9];
  const float* fb3 = (const float*)d_in[10];
  float* out = (float*)d_out;

  char* ws = (char*)d_ws;
  float*    part  = (float*)ws;                       // 32 MB
  uint8_t*  xq    = (uint8_t*)(ws + (32u << 20));     //  8 MB
  _Float16* afrag = (_Float16*)(ws + (41u << 20));    // 76 KB (conv2 + conv1 frags)
  _Float16* w1s   = (_Float16*)(ws + (42u << 20));    //  8 MB

  k_prep<<<dim3(1097), dim3(256), 0, stream>>>(w2c, w1c, fw1, afrag, w1s);
  k_conv<<<dim3(1024), dim3(256), 0, stream>>>(x, b1c, afrag, b2c, xq);
  k_fc1<<<dim3(512), dim3(256), 0, stream>>>(xq, w1s, part);
  k_lif<<<dim3(256), dim3(512), 0, stream>>>(part, fb1, fw2, fb2, fw3, fb3, out);
}

// Round 10
// 471.564 us; speedup vs baseline: 1.3077x; 1.3077x over previous
//
#include <hip/hip_runtime.h>
#include <stdint.h>

// AudioSNN: conv1(1->32)+spike+pool -> conv2(32->64)+spike+pool -> fc1
// -> 25-step LIF (fc2, fc3).
// conv2/fc1/fc2/fc3 on MFMA via exact fp16 2-way splits (err ~2^-23, absmax 0
// R3..R9). conv1 on VALU (R8 showed conv1-MFMA is not a win). R10: recover
// from R9 spill storm — launch_bounds STAYS (256,2) (R7+R9 lesson: a min-waves
// hint within ~20 regs of the live set = scratch spill storm; (256,3) is
// radioactive on k_conv). Upside levers that cannot spill: cin as u8
// (LDS 59.4->34.7 KB) + phase-2 split into two acc[4][4] passes; if actual
// reg allocation lands <=170, occupancy rises to 3 blocks/CU organically.
//
// ws layout:
//   part f32 [32][1024][256]       @0     32 MB
//   xq   u8  [1024][8192]          @32M    8 MB
//   afrag f16 [72][512]            @41M   72 KB (conv2 A fragments hi/lo)
//   w1s  f16 [2][16][256][512]     @42M    8 MB (fc1 A fragments hi/lo planes)

#define NSTEP 25

using half8   = __attribute__((ext_vector_type(8))) _Float16;
using half4v  = __attribute__((ext_vector_type(4))) _Float16;
using float4v = __attribute__((ext_vector_type(4))) float;

__device__ __forceinline__ float lif_update(float mem, float cur) {
#pragma clang fp contract(off)
  float reset = (mem > 1.0f) ? 1.0f : 0.0f;
  float m = 0.95f * mem;
  m = m + cur;
  m = m - reset;
  return m;
}

// ------------------------------------------------- weight prep (all fragments)
// blocks 0..71: conv2 afrag; blocks 72..1095: fc1 w1s.
__global__ __launch_bounds__(256) void k_prep(const float* __restrict__ w2c,
                                              const float* __restrict__ w1,
                                              _Float16* __restrict__ afrag,
                                              _Float16* __restrict__ w1s) {
  const int b = blockIdx.x;
  const int t = threadIdx.x;
  if (b < 72) {
    if (t < 64) {
      const int tp = b >> 3;
      const int mt = (b & 7) >> 1;
      const int sp = b & 1;
      const int m = t & 15, quad = t >> 4;
#pragma unroll
      for (int j = 0; j < 8; ++j) {
        int ch = quad * 8 + j;
        int oc = mt * 16 + m;
        float wv = w2c[(size_t)(oc * 32 + ch) * 9 + tp];
        float hi = (float)(_Float16)wv;
        _Float16 val = (sp == 0) ? (_Float16)wv : (_Float16)(wv - hi);
        afrag[(size_t)b * 512 + t * 8 + j] = val;
      }
    }
    return;
  }
  const int W = (b - 72) * 4 + (t >> 6);  // 0..4095 = mt*256+kcg
  const int lane = t & 63;
  const int mt = W >> 8, kcg = W & 255;
  const int m = lane & 15, quad = lane >> 4;
  const float* src = w1 + (size_t)(mt * 16 + m) * 8192 + kcg * 32 + quad * 8;
  float4 u0 = *(const float4*)src;
  float4 u1 = *(const float4*)(src + 4);
  float wv[8] = {u0.x, u0.y, u0.z, u0.w, u1.x, u1.y, u1.z, u1.w};
  half8 hi, lo;
#pragma unroll
  for (int e = 0; e < 8; ++e) {
    float h = (float)(_Float16)wv[e];
    hi[e] = (_Float16)wv[e];
    lo[e] = (_Float16)(wv[e] - h);
  }
  _Float16* dst = w1s + ((size_t)W) * 512 + lane * 8;
  *(half8*)dst = hi;
  *(half8*)(dst + (size_t)16 * 256 * 512) = lo;   // lo plane at +4 MB
}

// -------------------------------------------- fused conv1+conv2 (one sample)
// Phase 1 (VALU, exact fp32): conv1+spike+pool -> cin u8 counts (LDS).
// Phase 2 (MFMA 16x16x32): conv2 implicit GEMM, two acc[4][4] passes.
__global__ __launch_bounds__(256, 2) void k_conv(const float* __restrict__ x,
                                                 const float* __restrict__ w1c,
                                                 const float* __restrict__ b1c,
                                                 const _Float16* __restrict__ afrag,
                                                 const float* __restrict__ b2c,
                                                 uint8_t* __restrict__ xq) {
  __shared__ uint8_t cin[34 * 18 * 40];   // [row 34][col 18][ch pad 40] 24480 B
  __shared__ float xin[66 * 34];          // conv1 input + halo (fp32, exact)
  __shared__ float wl[288];
  __shared__ float bl[32];
  const int t = threadIdx.x;
  const int s = blockIdx.x;
  const int lane = t & 63;
  const int wave = __builtin_amdgcn_readfirstlane(t >> 6);

  {  // zero cin (covers halos) + xin
    uint4 z4 = {0u, 0u, 0u, 0u};
    uint4* cp = (uint4*)cin;
    for (int idx = t; idx < 1530; idx += 256) cp[idx] = z4;
    for (int idx = t; idx < 66 * 34; idx += 256) xin[idx] = 0.0f;
  }
  wl[t < 288 ? t : 0] = w1c[t < 288 ? t : 0];
  if (t < 32) { wl[256 + t] = w1c[256 + t]; bl[t] = b1c[t]; }
  __syncthreads();

  {  // stage x interior
    const float* xs = x + (size_t)s * (64 * 32);
#pragma unroll
    for (int r = 0; r < 2; ++r) {
      int idx = t + r * 256;              // 512 groups = 64 rows x 8 quads
      int y = idx >> 3, q = idx & 7;
      float4 v = *(const float4*)(xs + y * 32 + q * 4);
      float* dst = &xin[(y + 1) * 34 + q * 4 + 1];
      dst[0] = v.x; dst[1] = v.y; dst[2] = v.z; dst[3] = v.w;
    }
  }
  __syncthreads();

  // ---- phase 1: conv1 (exact fp32 VALU), spike+pool -> cin u8
  {
    const int ch = t & 31;
    const int po = t >> 5;
    float wc[9];
#pragma unroll
    for (int i = 0; i < 9; ++i) wc[i] = wl[ch * 9 + i];
    const float bv = bl[ch];
    for (int rr = 0; rr < 64; ++rr) {
      int pos = rr * 8 + po;
      int py = pos >> 4, px = pos & 15;
      float p[4][4];
#pragma unroll
      for (int rw = 0; rw < 4; ++rw) {
        float2 a = *(const float2*)&xin[(2 * py + rw) * 34 + 2 * px];
        float2 b = *(const float2*)&xin[(2 * py + rw) * 34 + 2 * px + 2];
        p[rw][0] = a.x; p[rw][1] = a.y; p[rw][2] = b.x; p[rw][3] = b.y;
      }
      int cnt = 0;
#pragma unroll
      for (int dy = 0; dy < 2; ++dy)
#pragma unroll
        for (int dx = 0; dx < 2; ++dx) {
          float acc = 0.0f;
#pragma unroll
          for (int ky = 0; ky < 3; ++ky)
#pragma unroll
            for (int kx = 0; kx < 3; ++kx)
              acc += wc[ky * 3 + kx] * p[dy + ky][dx + kx];
          float v = acc + bv;
          cnt += (v > 1.0f) ? 1 : 0;
        }
      cin[((py + 1) * 18 + (px + 1)) * 40 + ch] = (uint8_t)cnt;
    }
  }
  __syncthreads();

  // ---- phase 2: conv2 MFMA, two nt-halves (acc[4][4] = 64 regs live)
  const int xlane = lane & 15, quad = lane >> 4;

  float bw[4][4];
#pragma unroll
  for (int mt = 0; mt < 4; ++mt)
#pragma unroll
    for (int r = 0; r < 4; ++r) bw[mt][r] = b2c[mt * 16 + quad * 4 + r];

  uint8_t* xqs = xq + (size_t)s * 8192;
  const int px = xlane >> 1;
  const bool writer = (xlane & 1) == 0;

#pragma unroll 1
  for (int ntp = 0; ntp < 2; ++ntp) {
    float4v acc[4][4];
#pragma unroll
    for (int mt = 0; mt < 4; ++mt)
#pragma unroll
      for (int n4 = 0; n4 < 4; ++n4) acc[mt][n4] = (float4v){0.f, 0.f, 0.f, 0.f};

    for (int ky = 0; ky < 3; ++ky)
      for (int kx = 0; kx < 3; ++kx) {
        const int tp = ky * 3 + kx;
        half8 a[4][2];
#pragma unroll
        for (int mt = 0; mt < 4; ++mt)
#pragma unroll
          for (int sp = 0; sp < 2; ++sp)
            a[mt][sp] = *(const half8*)(afrag +
                          ((size_t)((tp * 4 + mt) * 2 + sp)) * 512 + lane * 8);
#pragma unroll
        for (int n4 = 0; n4 < 4; ++n4) {
          int row = wave * 8 + ntp * 4 + n4 + ky;
          int col = xlane + kx;
          const uint32_t* bp = (const uint32_t*)&cin[(row * 18 + col) * 40 + quad * 8];
          uint32_t w0 = bp[0], w1 = bp[1];      // 8B-aligned ds_read_b64
          half8 b;
#pragma unroll
          for (int e = 0; e < 4; ++e)
            b[e] = (_Float16)(float)((w0 >> (e * 8)) & 0xffu);
#pragma unroll
          for (int e = 0; e < 4; ++e)
            b[4 + e] = (_Float16)(float)((w1 >> (e * 8)) & 0xffu);
#pragma unroll
          for (int mt = 0; mt < 4; ++mt) {
            acc[mt][n4] = __builtin_amdgcn_mfma_f32_16x16x32_f16(a[mt][0], b,
                                                                 acc[mt][n4], 0, 0, 0);
            acc[mt][n4] = __builtin_amdgcn_mfma_f32_16x16x32_f16(a[mt][1], b,
                                                                 acc[mt][n4], 0, 0, 0);
          }
        }
      }

    // epilogue for this nt-half: pooled rows py = wave*4 + ntp*2 + {0,1}
#pragma unroll
    for (int mt = 0; mt < 4; ++mt)
#pragma unroll
      for (int pr2 = 0; pr2 < 2; ++pr2) {
        int py = wave * 4 + ntp * 2 + pr2;
#pragma unroll
        for (int r = 0; r < 4; ++r) {
          float v0 = 0.25f * acc[mt][2 * pr2 + 0][r] + bw[mt][r];
          float v1 = 0.25f * acc[mt][2 * pr2 + 1][r] + bw[mt][r];
          int c = ((v0 > 1.0f) ? 1 : 0) + ((v1 > 1.0f) ? 1 : 0);
          c += __shfl_xor(c, 1, 64);
          if (writer) {
            int oc = mt * 16 + quad * 4 + r;
            xqs[oc * 128 + py * 8 + px] = (uint8_t)c;
          }
        }
      }
  }
}

// ---------------------------------------------------------------- fc1 (MFMA)
__global__ __launch_bounds__(256, 2) void k_fc1(const uint8_t* __restrict__ xq,
                                                const _Float16* __restrict__ w1s,
                                                float* __restrict__ part) {
  __shared__ _Float16 bt[8 * 4 * 64 * 8];   // [kc][nt][lane][8] = 32 KB
  const int t = threadIdx.x;
  const int sblk = blockIdx.x >> 5;   // 16 sample tiles of 64
  const int kblk = blockIdx.x & 31;   // 32 K slices of 256
  const int sb = sblk * 64;

  {  // stage B: u8 counts -> fp16, frag-ready
    const int row = t >> 2;
    const int seg = t & 3;
    const int nt = row >> 4, n16 = row & 15;
    const uint8_t* src = xq + (size_t)(sb + row) * 8192 + kblk * 256 + seg * 64;
#pragma unroll
    for (int q = 0; q < 4; ++q) {
      uint4 u = *(const uint4*)(src + q * 16);
      uint32_t wd[4] = {u.x, u.y, u.z, u.w};
#pragma unroll
      for (int g = 0; g < 2; ++g) {
        half8 h;
#pragma unroll
        for (int e = 0; e < 8; ++e) {
          uint32_t word = wd[g * 2 + (e >> 2)];
          h[e] = (_Float16)(unsigned short)((word >> ((e & 3) * 8)) & 0xffu);
        }
        int koff = seg * 64 + q * 16 + g * 8;
        int kc = koff >> 5, quad = (koff >> 3) & 3;
        *(half8*)&bt[(((kc * 4 + nt) * 64) + quad * 16 + n16) * 8] = h;
      }
    }
  }
  __syncthreads();

  const int lane = t & 63;
  const int wave = __builtin_amdgcn_readfirstlane(t >> 6);

  float4v acc[4][4];
#pragma unroll
  for (int mt = 0; mt < 4; ++mt)
#pragma unroll
    for (int nt = 0; nt < 4; ++nt) acc[mt][nt] = (float4v){0.f, 0.f, 0.f, 0.f};

#pragma unroll
  for (int kc = 0; kc < 8; ++kc) {
    const int kcg = kblk * 8 + kc;
    half8 b[4];
#pragma unroll
    for (int nt = 0; nt < 4; ++nt)
      b[nt] = *(const half8*)&bt[((kc * 4 + nt) * 64 + lane) * 8];
#pragma unroll
    for (int mt = 0; mt < 4; ++mt) {
      const _Float16* ap = w1s + ((size_t)((wave * 4 + mt) * 256 + kcg)) * 512 + lane * 8;
      half8 ah = *(const half8*)ap;
      half8 al = *(const half8*)(ap + (size_t)16 * 256 * 512);
#pragma unroll
      for (int nt = 0; nt < 4; ++nt) {
        acc[mt][nt] = __builtin_amdgcn_mfma_f32_16x16x32_f16(ah, b[nt],
                                                             acc[mt][nt], 0, 0, 0);
        acc[mt][nt] = __builtin_amdgcn_mfma_f32_16x16x32_f16(al, b[nt],
                                                             acc[mt][nt], 0, 0, 0);
      }
    }
  }

  const int n16 = lane & 15, quad = lane >> 4;
  float* pp = part + (size_t)kblk * (1024 * 256);
#pragma unroll
  for (int mt = 0; mt < 4; ++mt)
#pragma unroll
    for (int nt = 0; nt < 4; ++nt) {
      int s = sb + nt * 16 + n16;
      int ob = wave * 64 + mt * 16 + quad * 4;
      float4 v = {0.25f * acc[mt][nt][0], 0.25f * acc[mt][nt][1],
                  0.25f * acc[mt][nt][2], 0.25f * acc[mt][nt][3]};
      *(float4*)&pp[(size_t)s * 256 + ob] = v;
    }
}

// ---------------------------------------------------------------- LIF recurrence
__global__ __launch_bounds__(512, 2) void k_lif(const float* __restrict__ part,
                                                const float* __restrict__ b1,
                                                const float* __restrict__ w2,   // [128][256]
                                                const float* __restrict__ b2,
                                                const float* __restrict__ w3,   // [10][128]
                                                const float* __restrict__ b3,
                                                float* __restrict__ out) {
  __shared__ float cur3l[1024];     // [s4][o256]
  __shared__ _Float16 spk3[1152];   // [oct32][s4][8] + pad
  __shared__ _Float16 spk4[640];    // [oct16][s4][8] + pad
  const int t = threadIdx.x;
  const int sb = blockIdx.x * 4;    // 4 samples/block, grid 256 = 1 block/CU
  const int lane = t & 63;
  const int wave = __builtin_amdgcn_readfirstlane(t >> 6);
  const int n16 = lane & 15;
  const int quad = lane >> 4;

  // ---- fc1 reduce: deterministic kb-order sum + bias-last
#pragma unroll
  for (int r = 0; r < 2; ++r) {
    int v = t + r * 512;            // = s*256 + o
    int s = v >> 8, o = v & 255;
    float sum = 0.0f;
    for (int kb = 0; kb < 32; ++kb)
      sum += part[(size_t)kb * (1024 * 256) + (size_t)(sb + s) * 256 + o];
    cur3l[v] = sum + b1[o];
  }

  half8 a2h[8], a2l[8];
  {
    const float* wr = w2 + (size_t)(wave * 16 + n16) * 256 + quad * 8;
#pragma unroll
    for (int kt = 0; kt < 8; ++kt) {
      float4 u0 = *(const float4*)(wr + kt * 32);
      float4 u1 = *(const float4*)(wr + kt * 32 + 4);
      float wv[8] = {u0.x, u0.y, u0.z, u0.w, u1.x, u1.y, u1.z, u1.w};
#pragma unroll
      for (int e = 0; e < 8; ++e) {
        float hi = (float)(_Float16)wv[e];
        a2h[kt][e] = (_Float16)wv[e];
        a2l[kt][e] = (_Float16)(wv[e] - hi);
      }
    }
  }
  const float4 b2v = *(const float4*)(b2 + wave * 16 + quad * 4);
  float mem4[4] = {0.f, 0.f, 0.f, 0.f};

  half8 a3h[4], a3l[4];
#pragma unroll
  for (int kt = 0; kt < 4; ++kt) { a3h[kt] = (half8){}; a3l[kt] = (half8){}; }
  if (n16 < 10) {
    const float* wr = w3 + (size_t)n16 * 128 + quad * 8;
#pragma unroll
    for (int kt = 0; kt < 4; ++kt) {
      float4 u0 = *(const float4*)(wr + kt * 32);
      float4 u1 = *(const float4*)(wr + kt * 32 + 4);
      float wv[8] = {u0.x, u0.y, u0.z, u0.w, u1.x, u1.y, u1.z, u1.w};
#pragma unroll
      for (int e = 0; e < 8; ++e) {
        float hi = (float)(_Float16)wv[e];
        a3h[kt][e] = (_Float16)wv[e];
        a3l[kt][e] = (_Float16)(wv[e] - hi);
      }
    }
  }
  float b3r[4];
#pragma unroll
  for (int r = 0; r < 4; ++r) {
    int cls = quad * 4 + r;
    b3r[r] = (cls < 10) ? b3[cls] : 0.0f;
  }
  float mem5[4] = {0.f, 0.f, 0.f, 0.f};

  __syncthreads();

  float mem3[8], cur3r[8];
  if (t < 128) {
    const int o = t >> 2, s = t & 3;
    const float* cp = &cur3l[s * 256 + o * 8];
    float4 c0 = *(const float4*)cp;
    float4 c1 = *(const float4*)(cp + 4);
    cur3r[0] = c0.x; cur3r[1] = c0.y; cur3r[2] = c0.z; cur3r[3] = c0.w;
    cur3r[4] = c1.x; cur3r[5] = c1.y; cur3r[6] = c1.z; cur3r[7] = c1.w;
#pragma unroll
    for (int j = 0; j < 8; ++j) mem3[j] = 0.0f;
  }

  for (int step = 0; step < NSTEP; ++step) {
    if (t < 128) {
      const int o = t >> 2, s = t & 3;
      half8 sv;
#pragma unroll
      for (int j = 0; j < 8; ++j) {
        mem3[j] = lif_update(mem3[j], cur3r[j]);
        sv[j] = (_Float16)((mem3[j] > 1.0f) ? 1.0f : 0.0f);
      }
      *(half8*)&spk3[o * 32 + s * 8] = sv;
    }
    __syncthreads();
    {
      float4v acc0 = {0.f, 0.f, 0.f, 0.f}, acc1 = {0.f, 0.f, 0.f, 0.f};
#pragma unroll
      for (int kt = 0; kt < 8; ++kt) {
        half8 b = *(const half8*)&spk3[(kt * 4 + quad) * 32 + n16 * 8];
        acc0 = __builtin_amdgcn_mfma_f32_16x16x32_f16(a2h[kt], b, acc0, 0, 0, 0);
        acc1 = __builtin_amdgcn_mfma_f32_16x16x32_f16(a2l[kt], b, acc1, 0, 0, 0);
      }
      if (n16 < 4) {
        half4v pk;
#pragma unroll
        for (int r = 0; r < 4; ++r) {
          float cur4 = (acc0[r] + acc1[r]) + b2v[r];
          mem4[r] = lif_update(mem4[r], cur4);
          pk[r] = (_Float16)((mem4[r] > 1.0f) ? 1.0f : 0.0f);
        }
        *(half4v*)&spk4[(wave * 2 + (quad >> 1)) * 32 + n16 * 8 + (quad & 1) * 4] = pk;
      }
    }
    __syncthreads();
    if (wave == 0) {
      float4v c0 = {0.f, 0.f, 0.f, 0.f}, c1 = {0.f, 0.f, 0.f, 0.f};
#pragma unroll
      for (int kt = 0; kt < 4; ++kt) {
        half8 b = *(const half8*)&spk4[(kt * 4 + quad) * 32 + n16 * 8];
        c0 = __builtin_amdgcn_mfma_f32_16x16x32_f16(a3h[kt], b, c0, 0, 0, 0);
        c1 = __builtin_amdgcn_mfma_f32_16x16x32_f16(a3l[kt], b, c1, 0, 0, 0);
      }
#pragma unroll
      for (int r = 0; r < 4; ++r) {
        int cls = quad * 4 + r;
        float cur5 = (c0[r] + c1[r]) + b3r[r];
        mem5[r] = lif_update(mem5[r], cur5);
        if (n16 < 4 && cls < 10)
          out[(size_t)step * 10240 + (size_t)(sb + n16) * 10 + cls] =
              (mem5[r] > 1.0f) ? 1.0f : 0.0f;
      }
    }
    __syncthreads();
  }
}

// ---------------------------------------------------------------- launcher
extern "C" void kernel_launch(void* const* d_in, const int* in_sizes, int n_in,
                              void* d_out, int out_size, void* d_ws, size_t ws_size,
                              hipStream_t stream) {
  (void)in_sizes; (void)n_in; (void)out_size; (void)ws_size;
  const float* x   = (const float*)d_in[0];
  const float* w1c = (const float*)d_in[1];
  const float* b1c = (const float*)d_in[2];
  const float* w2c = (const float*)d_in[3];
  const float* b2c = (const float*)d_in[4];
  const float* fw1 = (const float*)d_in[5];
  const float* fb1 = (const float*)d_in[6];
  const float* fw2 = (const float*)d_in[7];
  const float* fb2 = (const float*)d_in[8];
  const float* fw3 = (const float*)d_in[9];
  const float* fb3 = (const float*)d_in[10];
  float* out = (float*)d_out;

  char* ws = (char*)d_ws;
  float*    part  = (float*)ws;                       // 32 MB
  uint8_t*  xq    = (uint8_t*)(ws + (32u << 20));     //  8 MB
  _Float16* afrag = (_Float16*)(ws + (41u << 20));    // 72 KB
  _Float16* w1s   = (_Float16*)(ws + (42u << 20));    //  8 MB

  k_prep<<<dim3(1096), dim3(256), 0, stream>>>(w2c, fw1, afrag, w1s);
  k_conv<<<dim3(1024), dim3(256), 0, stream>>>(x, w1c, b1c, afrag, b2c, xq);
  k_fc1<<<dim3(512), dim3(256), 0, stream>>>(xq, w1s, part);
  k_lif<<<dim3(256), dim3(512), 0, stream>>>(part, fb1, fw2, fb2, fw3, fb3, out);
}

// Round 11
// 195.156 us; speedup vs baseline: 3.1597x; 2.4163x over previous
//
#include <hip/hip_runtime.h>
#include <stdint.h>

// AudioSNN: conv1(1->32)+spike+pool -> conv2(32->64)+spike+pool -> fc1
// -> 25-step LIF (fc2, fc3).
// conv2/fc1/fc2/fc3 on MFMA via exact fp16 2-way splits (err ~2^-23, absmax 0
// R3..R10). conv1 on VALU. R11: re-anchor at the best-known R6 structure.
// LESSONS (3 scratch storms): (a) launch_bounds min-waves near the live set
// spills (R7); (b) the u8-cin + nt-split phase-2 rewrite triggers a compiler
// scratch pathology even at (256,2) (R9/R10) — k_conv phase-2 must keep the
// R6/R8 shape: fp16 cin, monolithic acc[4][8], (256,2). Only R8-proven tweak
// kept: cin pad 36 + paired b64 B-loads (conflicts 0, spill-free in R8).
// k_conv is register-pool bound at 2 blocks/CU (acc 128 + ~100 arch ~= 228).
//
// ws layout:
//   part f32 [32][1024][256]       @0     32 MB
//   xq   u8  [1024][8192]          @32M    8 MB
//   afrag f16 [72][512]            @41M   72 KB (conv2 A fragments hi/lo)
//   w1s  f16 [2][16][256][512]     @42M    8 MB (fc1 A fragments hi/lo planes)

#define NSTEP 25

using half8   = __attribute__((ext_vector_type(8))) _Float16;
using half4v  = __attribute__((ext_vector_type(4))) _Float16;
using float4v = __attribute__((ext_vector_type(4))) float;

__device__ __forceinline__ float lif_update(float mem, float cur) {
#pragma clang fp contract(off)
  float reset = (mem > 1.0f) ? 1.0f : 0.0f;
  float m = 0.95f * mem;
  m = m + cur;
  m = m - reset;
  return m;
}

// ------------------------------------------------- weight prep (all fragments)
// blocks 0..71: conv2 afrag; blocks 72..1095: fc1 w1s.
__global__ __launch_bounds__(256) void k_prep(const float* __restrict__ w2c,
                                              const float* __restrict__ w1,
                                              _Float16* __restrict__ afrag,
                                              _Float16* __restrict__ w1s) {
  const int b = blockIdx.x;
  const int t = threadIdx.x;
  if (b < 72) {
    if (t < 64) {
      const int tp = b >> 3;
      const int mt = (b & 7) >> 1;
      const int sp = b & 1;
      const int m = t & 15, quad = t >> 4;
#pragma unroll
      for (int j = 0; j < 8; ++j) {
        int ch = quad * 8 + j;
        int oc = mt * 16 + m;
        float wv = w2c[(size_t)(oc * 32 + ch) * 9 + tp];
        float hi = (float)(_Float16)wv;
        _Float16 val = (sp == 0) ? (_Float16)wv : (_Float16)(wv - hi);
        afrag[(size_t)b * 512 + t * 8 + j] = val;
      }
    }
    return;
  }
  const int W = (b - 72) * 4 + (t >> 6);  // 0..4095 = mt*256+kcg
  const int lane = t & 63;
  const int mt = W >> 8, kcg = W & 255;
  const int m = lane & 15, quad = lane >> 4;
  const float* src = w1 + (size_t)(mt * 16 + m) * 8192 + kcg * 32 + quad * 8;
  float4 u0 = *(const float4*)src;
  float4 u1 = *(const float4*)(src + 4);
  float wv[8] = {u0.x, u0.y, u0.z, u0.w, u1.x, u1.y, u1.z, u1.w};
  half8 hi, lo;
#pragma unroll
  for (int e = 0; e < 8; ++e) {
    float h = (float)(_Float16)wv[e];
    hi[e] = (_Float16)wv[e];
    lo[e] = (_Float16)(wv[e] - h);
  }
  _Float16* dst = w1s + ((size_t)W) * 512 + lane * 8;
  *(half8*)dst = hi;
  *(half8*)(dst + (size_t)16 * 256 * 512) = lo;   // lo plane at +4 MB
}

// -------------------------------------------- fused conv1+conv2 (one sample)
// Phase 1 (VALU, exact fp32): conv1+spike+pool -> cin fp16 counts (LDS).
// Phase 2 (MFMA 16x16x32): conv2 implicit GEMM, monolithic acc[4][8] (R6 shape).
__global__ __launch_bounds__(256, 2) void k_conv(const float* __restrict__ x,
                                                 const float* __restrict__ w1c,
                                                 const float* __restrict__ b1c,
                                                 const _Float16* __restrict__ afrag,
                                                 const float* __restrict__ b2c,
                                                 uint8_t* __restrict__ xq) {
  __shared__ _Float16 cin[34 * 18 * 36];  // [row 34][col 18][ch pad 36] 44064 B
  __shared__ float xin[66 * 34];          // conv1 input + halo
  __shared__ float wl[288];
  __shared__ float bl[32];
  const int t = threadIdx.x;
  const int s = blockIdx.x;

  {  // zero cin (covers halos), stage conv1 weights + input
    half8* cp = (half8*)cin;
    half8 z = {};
    for (int idx = t; idx < 2754; idx += 256) cp[idx] = z;
  }
  for (int idx = t; idx < 66 * 34; idx += 256) xin[idx] = 0.0f;
  wl[t] = w1c[t];
  if (t < 32) { wl[256 + t] = w1c[256 + t]; bl[t] = b1c[t]; }
  __syncthreads();

  const float* xs = x + (size_t)s * (64 * 32);
#pragma unroll
  for (int r = 0; r < 2; ++r) {
    int idx = t + r * 256;
    int y = idx >> 3, q = idx & 7;
    float4 v = *(const float4*)(xs + y * 32 + q * 4);
    float* dst = &xin[(y + 1) * 34 + q * 4 + 1];
    dst[0] = v.x; dst[1] = v.y; dst[2] = v.z; dst[3] = v.w;
  }
  __syncthreads();

  // ---- phase 1: conv1 (exact fp32 VALU), spike+pool -> cin fp16 counts
  {
    const int ch = t & 31;
    const int po = t >> 5;
    float wc[9];
#pragma unroll
    for (int i = 0; i < 9; ++i) wc[i] = wl[ch * 9 + i];
    const float bv = bl[ch];
    for (int rr = 0; rr < 64; ++rr) {
      int pos = rr * 8 + po;
      int py = pos >> 4, px = pos & 15;
      float p[4][4];
#pragma unroll
      for (int rw = 0; rw < 4; ++rw) {
        float2 a = *(const float2*)&xin[(2 * py + rw) * 34 + 2 * px];
        float2 b = *(const float2*)&xin[(2 * py + rw) * 34 + 2 * px + 2];
        p[rw][0] = a.x; p[rw][1] = a.y; p[rw][2] = b.x; p[rw][3] = b.y;
      }
      int cnt = 0;
#pragma unroll
      for (int dy = 0; dy < 2; ++dy)
#pragma unroll
        for (int dx = 0; dx < 2; ++dx) {
          float acc = 0.0f;
#pragma unroll
          for (int ky = 0; ky < 3; ++ky)
#pragma unroll
            for (int kx = 0; kx < 3; ++kx)
              acc += wc[ky * 3 + kx] * p[dy + ky][dx + kx];
          float v = acc + bv;
          cnt += (v > 1.0f) ? 1 : 0;
        }
      cin[((py + 1) * 18 + (px + 1)) * 36 + ch] = (_Float16)(float)cnt;
    }
  }
  __syncthreads();

  // ---- phase 2: conv2 MFMA (M=64 oc, N=512 pos, K=32 ch per tap x 9)
  const int lane = t & 63;
  const int wave = __builtin_amdgcn_readfirstlane(t >> 6);
  const int xlane = lane & 15, quad = lane >> 4;

  float4v acc[4][8];
#pragma unroll
  for (int mt = 0; mt < 4; ++mt)
#pragma unroll
    for (int nt = 0; nt < 8; ++nt) acc[mt][nt] = (float4v){0.f, 0.f, 0.f, 0.f};

  for (int ky = 0; ky < 3; ++ky)
    for (int kx = 0; kx < 3; ++kx) {
      const int tp = ky * 3 + kx;
      half8 a[4][2];
#pragma unroll
      for (int mt = 0; mt < 4; ++mt)
#pragma unroll
        for (int sp = 0; sp < 2; ++sp)
          a[mt][sp] = *(const half8*)(afrag +
                        ((size_t)((tp * 4 + mt) * 2 + sp)) * 512 + lane * 8);
#pragma unroll
      for (int nt = 0; nt < 8; ++nt) {
        int row = wave * 8 + nt + ky;
        int col = xlane + kx;
        const _Float16* bp = &cin[(row * 18 + col) * 36 + quad * 8];
        half8 b;
        *(half4v*)&b = *(const half4v*)bp;          // 8B-aligned (pad 36)
        *((half4v*)&b + 1) = *(const half4v*)(bp + 4);
#pragma unroll
        for (int mt = 0; mt < 4; ++mt) {
          acc[mt][nt] = __builtin_amdgcn_mfma_f32_16x16x32_f16(a[mt][0], b,
                                                               acc[mt][nt], 0, 0, 0);
          acc[mt][nt] = __builtin_amdgcn_mfma_f32_16x16x32_f16(a[mt][1], b,
                                                               acc[mt][nt], 0, 0, 0);
        }
      }
    }

  float bw[4][4];
#pragma unroll
  for (int mt = 0; mt < 4; ++mt)
#pragma unroll
    for (int r = 0; r < 4; ++r) bw[mt][r] = b2c[mt * 16 + quad * 4 + r];

  uint8_t* xqs = xq + (size_t)s * 8192;
  const int px = xlane >> 1;
  const bool writer = (xlane & 1) == 0;
#pragma unroll
  for (int mt = 0; mt < 4; ++mt)
#pragma unroll
    for (int ntp = 0; ntp < 4; ++ntp) {
      int py = wave * 4 + ntp;
#pragma unroll
      for (int r = 0; r < 4; ++r) {
        float v0 = 0.25f * acc[mt][2 * ntp + 0][r] + bw[mt][r];
        float v1 = 0.25f * acc[mt][2 * ntp + 1][r] + bw[mt][r];
        int c = ((v0 > 1.0f) ? 1 : 0) + ((v1 > 1.0f) ? 1 : 0);
        c += __shfl_xor(c, 1, 64);
        if (writer) {
          int oc = mt * 16 + quad * 4 + r;
          xqs[oc * 128 + py * 8 + px] = (uint8_t)c;
        }
      }
    }
}

// ---------------------------------------------------------------- fc1 (MFMA)
__global__ __launch_bounds__(256, 2) void k_fc1(const uint8_t* __restrict__ xq,
                                                const _Float16* __restrict__ w1s,
                                                float* __restrict__ part) {
  __shared__ _Float16 bt[8 * 4 * 64 * 8];   // [kc][nt][lane][8] = 32 KB
  const int t = threadIdx.x;
  const int sblk = blockIdx.x >> 5;   // 16 sample tiles of 64
  const int kblk = blockIdx.x & 31;   // 32 K slices of 256
  const int sb = sblk * 64;

  {  // stage B: u8 counts -> fp16, frag-ready
    const int row = t >> 2;
    const int seg = t & 3;
    const int nt = row >> 4, n16 = row & 15;
    const uint8_t* src = xq + (size_t)(sb + row) * 8192 + kblk * 256 + seg * 64;
#pragma unroll
    for (int q = 0; q < 4; ++q) {
      uint4 u = *(const uint4*)(src + q * 16);
      uint32_t wd[4] = {u.x, u.y, u.z, u.w};
#pragma unroll
      for (int g = 0; g < 2; ++g) {
        half8 h;
#pragma unroll
        for (int e = 0; e < 8; ++e) {
          uint32_t word = wd[g * 2 + (e >> 2)];
          h[e] = (_Float16)(unsigned short)((word >> ((e & 3) * 8)) & 0xffu);
        }
        int koff = seg * 64 + q * 16 + g * 8;
        int kc = koff >> 5, quad = (koff >> 3) & 3;
        *(half8*)&bt[(((kc * 4 + nt) * 64) + quad * 16 + n16) * 8] = h;
      }
    }
  }
  __syncthreads();

  const int lane = t & 63;
  const int wave = __builtin_amdgcn_readfirstlane(t >> 6);

  float4v acc[4][4];
#pragma unroll
  for (int mt = 0; mt < 4; ++mt)
#pragma unroll
    for (int nt = 0; nt < 4; ++nt) acc[mt][nt] = (float4v){0.f, 0.f, 0.f, 0.f};

#pragma unroll
  for (int kc = 0; kc < 8; ++kc) {
    const int kcg = kblk * 8 + kc;
    half8 b[4];
#pragma unroll
    for (int nt = 0; nt < 4; ++nt)
      b[nt] = *(const half8*)&bt[((kc * 4 + nt) * 64 + lane) * 8];
#pragma unroll
    for (int mt = 0; mt < 4; ++mt) {
      const _Float16* ap = w1s + ((size_t)((wave * 4 + mt) * 256 + kcg)) * 512 + lane * 8;
      half8 ah = *(const half8*)ap;
      half8 al = *(const half8*)(ap + (size_t)16 * 256 * 512);
#pragma unroll
      for (int nt = 0; nt < 4; ++nt) {
        acc[mt][nt] = __builtin_amdgcn_mfma_f32_16x16x32_f16(ah, b[nt],
                                                             acc[mt][nt], 0, 0, 0);
        acc[mt][nt] = __builtin_amdgcn_mfma_f32_16x16x32_f16(al, b[nt],
                                                             acc[mt][nt], 0, 0, 0);
      }
    }
  }

  const int n16 = lane & 15, quad = lane >> 4;
  float* pp = part + (size_t)kblk * (1024 * 256);
#pragma unroll
  for (int mt = 0; mt < 4; ++mt)
#pragma unroll
    for (int nt = 0; nt < 4; ++nt) {
      int s = sb + nt * 16 + n16;
      int ob = wave * 64 + mt * 16 + quad * 4;
      float4 v = {0.25f * acc[mt][nt][0], 0.25f * acc[mt][nt][1],
                  0.25f * acc[mt][nt][2], 0.25f * acc[mt][nt][3]};
      *(float4*)&pp[(size_t)s * 256 + ob] = v;
    }
}

// ---------------------------------------------------------------- LIF recurrence
__global__ __launch_bounds__(512, 2) void k_lif(const float* __restrict__ part,
                                                const float* __restrict__ b1,
                                                const float* __restrict__ w2,   // [128][256]
                                                const float* __restrict__ b2,
                                                const float* __restrict__ w3,   // [10][128]
                                                const float* __restrict__ b3,
                                                float* __restrict__ out) {
  __shared__ float cur3l[1024];     // [s4][o256]
  __shared__ _Float16 spk3[1152];   // [oct32][s4][8] + pad
  __shared__ _Float16 spk4[640];    // [oct16][s4][8] + pad
  const int t = threadIdx.x;
  const int sb = blockIdx.x * 4;    // 4 samples/block, grid 256 = 1 block/CU
  const int lane = t & 63;
  const int wave = __builtin_amdgcn_readfirstlane(t >> 6);
  const int n16 = lane & 15;
  const int quad = lane >> 4;

  // ---- fc1 reduce: deterministic kb-order sum + bias-last
#pragma unroll
  for (int r = 0; r < 2; ++r) {
    int v = t + r * 512;            // = s*256 + o
    int s = v >> 8, o = v & 255;
    float sum = 0.0f;
    for (int kb = 0; kb < 32; ++kb)
      sum += part[(size_t)kb * (1024 * 256) + (size_t)(sb + s) * 256 + o];
    cur3l[v] = sum + b1[o];
  }

  half8 a2h[8], a2l[8];
  {
    const float* wr = w2 + (size_t)(wave * 16 + n16) * 256 + quad * 8;
#pragma unroll
    for (int kt = 0; kt < 8; ++kt) {
      float4 u0 = *(const float4*)(wr + kt * 32);
      float4 u1 = *(const float4*)(wr + kt * 32 + 4);
      float wv[8] = {u0.x, u0.y, u0.z, u0.w, u1.x, u1.y, u1.z, u1.w};
#pragma unroll
      for (int e = 0; e < 8; ++e) {
        float hi = (float)(_Float16)wv[e];
        a2h[kt][e] = (_Float16)wv[e];
        a2l[kt][e] = (_Float16)(wv[e] - hi);
      }
    }
  }
  const float4 b2v = *(const float4*)(b2 + wave * 16 + quad * 4);
  float mem4[4] = {0.f, 0.f, 0.f, 0.f};

  half8 a3h[4], a3l[4];
#pragma unroll
  for (int kt = 0; kt < 4; ++kt) { a3h[kt] = (half8){}; a3l[kt] = (half8){}; }
  if (n16 < 10) {
    const float* wr = w3 + (size_t)n16 * 128 + quad * 8;
#pragma unroll
    for (int kt = 0; kt < 4; ++kt) {
      float4 u0 = *(const float4*)(wr + kt * 32);
      float4 u1 = *(const float4*)(wr + kt * 32 + 4);
      float wv[8] = {u0.x, u0.y, u0.z, u0.w, u1.x, u1.y, u1.z, u1.w};
#pragma unroll
      for (int e = 0; e < 8; ++e) {
        float hi = (float)(_Float16)wv[e];
        a3h[kt][e] = (_Float16)wv[e];
        a3l[kt][e] = (_Float16)(wv[e] - hi);
      }
    }
  }
  float b3r[4];
#pragma unroll
  for (int r = 0; r < 4; ++r) {
    int cls = quad * 4 + r;
    b3r[r] = (cls < 10) ? b3[cls] : 0.0f;
  }
  float mem5[4] = {0.f, 0.f, 0.f, 0.f};

  __syncthreads();

  float mem3[8], cur3r[8];
  if (t < 128) {
    const int o = t >> 2, s = t & 3;
    const float* cp = &cur3l[s * 256 + o * 8];
    float4 c0 = *(const float4*)cp;
    float4 c1 = *(const float4*)(cp + 4);
    cur3r[0] = c0.x; cur3r[1] = c0.y; cur3r[2] = c0.z; cur3r[3] = c0.w;
    cur3r[4] = c1.x; cur3r[5] = c1.y; cur3r[6] = c1.z; cur3r[7] = c1.w;
#pragma unroll
    for (int j = 0; j < 8; ++j) mem3[j] = 0.0f;
  }

  for (int step = 0; step < NSTEP; ++step) {
    if (t < 128) {
      const int o = t >> 2, s = t & 3;
      half8 sv;
#pragma unroll
      for (int j = 0; j < 8; ++j) {
        mem3[j] = lif_update(mem3[j], cur3r[j]);
        sv[j] = (_Float16)((mem3[j] > 1.0f) ? 1.0f : 0.0f);
      }
      *(half8*)&spk3[o * 32 + s * 8] = sv;
    }
    __syncthreads();
    {
      float4v acc0 = {0.f, 0.f, 0.f, 0.f}, acc1 = {0.f, 0.f, 0.f, 0.f};
#pragma unroll
      for (int kt = 0; kt < 8; ++kt) {
        half8 b = *(const half8*)&spk3[(kt * 4 + quad) * 32 + n16 * 8];
        acc0 = __builtin_amdgcn_mfma_f32_16x16x32_f16(a2h[kt], b, acc0, 0, 0, 0);
        acc1 = __builtin_amdgcn_mfma_f32_16x16x32_f16(a2l[kt], b, acc1, 0, 0, 0);
      }
      if (n16 < 4) {
        half4v pk;
#pragma unroll
        for (int r = 0; r < 4; ++r) {
          float cur4 = (acc0[r] + acc1[r]) + b2v[r];
          mem4[r] = lif_update(mem4[r], cur4);
          pk[r] = (_Float16)((mem4[r] > 1.0f) ? 1.0f : 0.0f);
        }
        *(half4v*)&spk4[(wave * 2 + (quad >> 1)) * 32 + n16 * 8 + (quad & 1) * 4] = pk;
      }
    }
    __syncthreads();
    if (wave == 0) {
      float4v c0 = {0.f, 0.f, 0.f, 0.f}, c1 = {0.f, 0.f, 0.f, 0.f};
#pragma unroll
      for (int kt = 0; kt < 4; ++kt) {
        half8 b = *(const half8*)&spk4[(kt * 4 + quad) * 32 + n16 * 8];
        c0 = __builtin_amdgcn_mfma_f32_16x16x32_f16(a3h[kt], b, c0, 0, 0, 0);
        c1 = __builtin_amdgcn_mfma_f32_16x16x32_f16(a3l[kt], b, c1, 0, 0, 0);
      }
#pragma unroll
      for (int r = 0; r < 4; ++r) {
        int cls = quad * 4 + r;
        float cur5 = (c0[r] + c1[r]) + b3r[r];
        mem5[r] = lif_update(mem5[r], cur5);
        if (n16 < 4 && cls < 10)
          out[(size_t)step * 10240 + (size_t)(sb + n16) * 10 + cls] =
              (mem5[r] > 1.0f) ? 1.0f : 0.0f;
      }
    }
    __syncthreads();
  }
}

// ---------------------------------------------------------------- launcher
extern "C" void kernel_launch(void* const* d_in, const int* in_sizes, int n_in,
                              void* d_out, int out_size, void* d_ws, size_t ws_size,
                              hipStream_t stream) {
  (void)in_sizes; (void)n_in; (void)out_size; (void)ws_size;
  const float* x   = (const float*)d_in[0];
  const float* w1c = (const float*)d_in[1];
  const float* b1c = (const float*)d_in[2];
  const float* w2c = (const float*)d_in[3];
  const float* b2c = (const float*)d_in[4];
  const float* fw1 = (const float*)d_in[5];
  const float* fb1 = (const float*)d_in[6];
  const float* fw2 = (const float*)d_in[7];
  const float* fb2 = (const float*)d_in[8];
  const float* fw3 = (const float*)d_in[9];
  const float* fb3 = (const float*)d_in[10];
  float* out = (float*)d_out;

  char* ws = (char*)d_ws;
  float*    part  = (float*)ws;                       // 32 MB
  uint8_t*  xq    = (uint8_t*)(ws + (32u << 20));     //  8 MB
  _Float16* afrag = (_Float16*)(ws + (41u << 20));    // 72 KB
  _Float16* w1s   = (_Float16*)(ws + (42u << 20));    //  8 MB

  k_prep<<<dim3(1096), dim3(256), 0, stream>>>(w2c, fw1, afrag, w1s);
  k_conv<<<dim3(1024), dim3(256), 0, stream>>>(x, w1c, b1c, afrag, b2c, xq);
  k_fc1<<<dim3(512), dim3(256), 0, stream>>>(xq, w1s, part);
  k_lif<<<dim3(256), dim3(512), 0, stream>>>(part, fb1, fw2, fb2, fw3, fb3, out);
}